// Round 3
// baseline (64.920 us; speedup 1.0000x reference)
//
#include <hip/hip_runtime.h>

// GMP (generalized memory polynomial), B=32, T=4096, M=11, DEG=5 (K=4 powers).
//
// out[b,t] = sum_{m=0..10} xc[b,t+m-10] *
//              ( W0[m] + sum_{k=1..4} sum_{l=0..10} |xc[b,t+l+m-20]|^k * W1[k-1,l,m] )
// with xc zero-padded for negative time indices.
// W0[m] = Weight[m]; W1[k,l,m] = Weight[11 + k*121 + l*11 + m].
//
// ROUND-5 RESTRUCTURE: 1 thread = 1 full output (was: 8-way wave split +
// LDS psum reduction). Rationale: total work is only ~138 MFLOP (<2 us at
// 50% of fp32 peak); the split's cross-wave reduction, 3 barriers, and
// 1/8-active epilogue dominated. Per thread: 484 FMA with 11 independent
// accumulator chains (ample ILP at 2 waves/SIMD); all weight indices are
// wave-uniform compile-time constants -> weights ride the scalar pipe
// (s_load), leaving VALU purely for FMAs. LDS reads are lane-consecutive
// (conflict-free). One barrier total; every lane stores its own float2.
//
// (Rounds 6-7 = identical resubmits: benches failed with
// GPUAcquisitionTimeout before launch — no data, no kernel change.)

#define GMP_M 11
#define GMP_T 4096
#define GMP_B 32
#define TILE 128
#define HALO 20          // 2*(M-1)
#define NTHREADS 128     // 2 waves; grid = (4096/128)*32 = 1024 blocks = 4/CU

__global__ __launch_bounds__(NTHREADS) void gmp_kernel(const float* __restrict__ x,
                                                       const float* __restrict__ W,
                                                       float* __restrict__ out) {
    const int b  = blockIdx.y;
    const int t0 = blockIdx.x * TILE;
    const int lt = threadIdx.x;

    __shared__ float2 xs[TILE + HALO];       // xc[b, t0-20+i]
    __shared__ float  pk[4][TILE + HALO];    // SoA power channels: a, a^2, a^3, a^4

    const float2* xb = (const float2*)(x + (size_t)b * GMP_T * 2);

    // Stage x tile + halo and the 4 power channels. 148 elems / 128 threads.
    for (int i = lt; i < TILE + HALO; i += NTHREADS) {
        int g = t0 - HALO + i;
        float2 v = make_float2(0.f, 0.f);
        if (g >= 0) v = xb[g];               // upper bound: g <= t0+TILE-1 <= T-1
        xs[i] = v;
        float r2 = v.x * v.x + v.y * v.y;
        float a  = sqrtf(r2);
        pk[0][i] = a;
        pk[1][i] = r2;
        pk[2][i] = r2 * a;
        pk[3][i] = r2 * r2;
    }
    __syncthreads();

    // gm[m] = W0[m] + sum_{k,l} P_k[t+l+m-20] * W1[k,l,m]
    float gm[GMP_M];
#pragma unroll
    for (int m = 0; m < GMP_M; ++m) gm[m] = W[m];      // uniform addr -> s_load

#pragma unroll
    for (int k = 0; k < 4; ++k) {
        // This thread's 21-entry window of power channel k (VGPR-resident,
        // constant indexing only after unroll). Lane-consecutive -> no conflicts.
        float P[HALO + 1];
#pragma unroll
        for (int s = 0; s <= HALO; ++s) P[s] = pk[k][lt + s];

        const float* __restrict__ Wk = W + GMP_M + k * (GMP_M * GMP_M);
#pragma unroll
        for (int l = 0; l < GMP_M; ++l)
#pragma unroll
            for (int m = 0; m < GMP_M; ++m)
                gm[m] += P[l + m] * Wk[l * GMP_M + m];  // v_fmac with SGPR weight
    }

    // Complex taps: acc = sum_m xc[t+m-10] * gm[m]
    float2 acc = make_float2(0.f, 0.f);
#pragma unroll
    for (int m = 0; m < GMP_M; ++m) {
        float2 xv = xs[lt + m + (GMP_M - 1)];
        acc.x += xv.x * gm[m];
        acc.y += xv.y * gm[m];
    }

    float2* ob = (float2*)(out + ((size_t)b * GMP_T + t0) * 2);
    ob[lt] = acc;
}

extern "C" void kernel_launch(void* const* d_in, const int* in_sizes, int n_in,
                              void* d_out, int out_size, void* d_ws, size_t ws_size,
                              hipStream_t stream) {
    (void)in_sizes; (void)n_in; (void)d_ws; (void)ws_size; (void)out_size;
    const float* x = (const float*)d_in[0];
    // d_in[1] is h_0 (unused by the reference computation)
    const float* W = (const float*)d_in[2];
    float* out = (float*)d_out;

    dim3 grid(GMP_T / TILE, GMP_B, 1);   // 32 x 32 = 1024 blocks
    dim3 block(NTHREADS, 1, 1);
    gmp_kernel<<<grid, block, 0, stream>>>(x, W, out);
}